// Round 7
// baseline (755.667 us; speedup 1.0000x reference)
//
#include <hip/hip_runtime.h>
#include <cstdint>
#include <cstddef>

#define BATCH 256
#define VOCAB 128000
#define V4 (VOCAB/4)
#define BVTOT 32768000
#define NBINS 4096
#define CAP 4096            // power of 2: bitonic padding can never overflow
#define CHUNKS 8
#define CHUNK_F4 (V4/CHUNKS)      // 4000 float4 per chunk

// ---- arena carved from the tail of d_out (d_out is fully rewritten each launch) ----
// hcnt: 256*4096 u32 | hmass: 256*4096 f32 | wmax: 2048 f32 | wdp: 2048 f32
#define HIST_U32   (2*NBINS*BATCH)                  // 2,097,152
#define ARENA_F    (HIST_U32 + 4096)                // 2,101,248 floats
#define ABASE      (BVTOT - ARENA_F)                // 30,666,752
#define FILL_ROWS  239                              // rows 0..238 end at 30,592,000 <= ABASE
#define TAIL_F4    ((BVTOT - FILL_ROWS*VOCAB)/4)    // 544,000 float4 filled by K4

__device__ __forceinline__ uint32_t rotl32(uint32_t v, int r){ return (v<<r)|(v>>(32-r)); }

// threefry2x32 with key (0,1) — jax.random.key(1) -> key data [0,1]
__device__ __forceinline__ void threefry2x32_01(uint32_t& x0, uint32_t& x1){
  const uint32_t ks0=0u, ks1=1u, ks2=0x1BD11BDAu ^ 0u ^ 1u;
  x0+=ks0; x1+=ks1;
#define TF_R(r) { x0+=x1; x1=rotl32(x1,(r)); x1^=x0; }
  TF_R(13) TF_R(15) TF_R(26) TF_R(6)
  x0+=ks1; x1+=ks2+1u;
  TF_R(17) TF_R(29) TF_R(16) TF_R(24)
  x0+=ks2; x1+=ks0+2u;
  TF_R(13) TF_R(15) TF_R(26) TF_R(6)
  x0+=ks0; x1+=ks1+3u;
  TF_R(17) TF_R(29) TF_R(16) TF_R(24)
  x0+=ks1; x1+=ks2+4u;
  TF_R(13) TF_R(15) TF_R(26) TF_R(6)
  x0+=ks2; x1+=ks0+5u;
#undef TF_R
}

// JAX partitionable threefry 32-bit draw: counter=(0,z), bits = x0 ^ x1 (XOR-fold).
// Verified correct in R4/R5 (absmax 0).
__device__ __forceinline__ float gumbel_at(uint32_t z){
  uint32_t x0 = 0u, x1 = z;
  threefry2x32_01(x0, x1);
  uint32_t bits = x0 ^ x1;
  uint32_t fb = (bits >> 9) | 0x3F800000u;
  float f = __uint_as_float(fb) - 1.0f;
  const float tiny = 1.17549435e-38f;
  float u = fmaxf(tiny, f + tiny);
  return -logf(-logf(u));
}

__device__ __forceinline__ uint32_t fkey(uint32_t u){
  return (u >> 31) ? ~u : (u | 0x80000000u);
}
__device__ __forceinline__ float pdecode(unsigned long long k){
  return __uint_as_float(~(uint32_t)(k >> 32));
}

// K1 (8 blocks/row, 256 thr): zero hist slice (exactly 1024 u32/block) + fill out
// chunk (rows < FILL_ROWS only) + chunk max -> wmax[bid].
__global__ __launch_bounds__(256) void k_fill_max(
    const float* __restrict__ scores, const float* __restrict__ green,
    float* __restrict__ out, float* __restrict__ wmax, unsigned* __restrict__ hzero)
{
  __shared__ float red[256];
  const int bid = blockIdx.x, tid = threadIdx.x;
  const int r = bid >> 3, c = bid & 7;
  {
    unsigned base = (unsigned)bid * 1024u;
    #pragma unroll
    for (int k = 0; k < 4; ++k) hzero[base + tid + 256*k] = 0u;  // 2048*1024 == HIST_U32 exactly
  }
  const float4* row4 = (const float4*)(scores + (size_t)r * VOCAB);
  const float4* grn4 = (const float4*)green;
  float4* out4 = (float4*)(out + (size_t)r * VOCAB);
  const float4 fv = make_float4(1e-5f, 1e-5f, 1e-5f, 1e-5f);
  float lm = -INFINITY;
  const int lo = c * CHUNK_F4, hi = lo + CHUNK_F4;
  if (r < FILL_ROWS){
    for (int i = lo + tid; i < hi; i += 256){
      float4 s = row4[i], g = grn4[i];
      out4[i] = fv;
      lm = fmaxf(lm, fmaf(2.f, g.x, s.x));
      lm = fmaxf(lm, fmaf(2.f, g.y, s.y));
      lm = fmaxf(lm, fmaf(2.f, g.z, s.z));
      lm = fmaxf(lm, fmaf(2.f, g.w, s.w));
    }
  } else {
    for (int i = lo + tid; i < hi; i += 256){
      float4 s = row4[i], g = grn4[i];
      lm = fmaxf(lm, fmaf(2.f, g.x, s.x));
      lm = fmaxf(lm, fmaf(2.f, g.y, s.y));
      lm = fmaxf(lm, fmaf(2.f, g.z, s.z));
      lm = fmaxf(lm, fmaf(2.f, g.w, s.w));
    }
  }
  red[tid] = lm; __syncthreads();
  for (int s = 128; s > 0; s >>= 1){ if (tid < s) red[tid] = fmaxf(red[tid], red[tid+s]); __syncthreads(); }
  if (tid == 0) wmax[bid] = red[0];
}

// K2 (8 blocks/row, 256 thr): m from 8 chunk maxes; partial sum(exp) -> wdp[bid];
// gated global histogram atomics (cnt uint, mass float) into the d_out arena.
__global__ __launch_bounds__(256) void k_dsum_hist(
    const float* __restrict__ scores, const float* __restrict__ green,
    const float* __restrict__ wmax, float* __restrict__ wdp,
    unsigned* __restrict__ hcnt, float* __restrict__ hmass)
{
  __shared__ float red[256];
  const int bid = blockIdx.x, tid = threadIdx.x;
  const int r = bid >> 3, c = bid & 7;
  float m = wmax[r*8+0];
  #pragma unroll
  for (int k = 1; k < 8; ++k) m = fmaxf(m, wmax[r*8+k]);
  const float hgate = m - 13.0f;     // excluded hist mass << 0.903-target margin (R5-proven)
  const float4* row4 = (const float4*)(scores + (size_t)r * VOCAB);
  const float4* grn4 = (const float4*)green;
  unsigned* hc = hcnt + (size_t)r * NBINS;
  float*    hm = hmass + (size_t)r * NBINS;
  float ls = 0.f;
  const int lo = c * CHUNK_F4, hi = lo + CHUNK_F4;
  for (int i = lo + tid; i < hi; i += 256){
    float4 s = row4[i], g = grn4[i];
    #pragma unroll
    for (int cc = 0; cc < 4; ++cc){
      float l = fmaf(2.f, (&g.x)[cc], (&s.x)[cc]);
      float e = expf(l - m);
      ls += e;
      if (l >= hgate){
        uint32_t bin = fkey(__float_as_uint(l)) >> 20;
        atomicAdd(&hc[bin], 1u);
        atomicAdd(&hm[bin], e);
      }
    }
  }
  red[tid] = ls; __syncthreads();
  for (int s = 128; s > 0; s >>= 1){ if (tid < s) red[tid] += red[tid+s]; __syncthreads(); }
  if (tid == 0) wdp[bid] = red[0];
}

// K3 (1 block/row, 1024 thr): hist->LDS, scan -> thr; extract -> LDS keys;
// re-encode p; bitonic sort; 0.9 cumsum crossing; gumbel argmax; ntok -> ws.
__global__ __launch_bounds__(1024) void k_sample(
    const float* __restrict__ scores, const float* __restrict__ green,
    const float* __restrict__ wmax, const float* __restrict__ wdp,
    const unsigned* __restrict__ hcnt, const float* __restrict__ hmass,
    unsigned* __restrict__ ntok)
{
  __shared__ union {
    struct { unsigned cnt[NBINS]; float mass[NBINS]; } h;  // 32 KB
    unsigned long long skeys[CAP];                         // 32 KB
  } u;
  __shared__ float red[1024];
  __shared__ unsigned long long wavewin[16];
  __shared__ unsigned n_sh, thr_sh;
  __shared__ int cut_sh;

  const int r = blockIdx.x, tid = threadIdx.x;
  float m = wmax[r*8+0];
  #pragma unroll
  for (int k = 1; k < 8; ++k) m = fmaxf(m, wmax[r*8+k]);
  float D = wdp[r*8+0];
  #pragma unroll
  for (int k = 1; k < 8; ++k) D += wdp[r*8+k];   // fixed order: deterministic

  for (int i = tid; i < NBINS; i += 1024){
    u.h.cnt[i]  = hcnt[(size_t)r * NBINS + i];
    u.h.mass[i] = hmass[(size_t)r * NBINS + i];
  }
  __syncthreads();

  if (tid == 0){
    float target = 0.903f * D;
    int top = (int)(fkey(__float_as_uint(m)) >> 20);
    float acc = 0.f; unsigned c = 0; unsigned result = (unsigned)top;
    for (int bin = top; bin >= 0; --bin){
      unsigned cb = u.h.cnt[bin];
      if (c + cb > CAP) break;
      acc += u.h.mass[bin]; c += cb; result = (unsigned)bin;
      if (acc >= target){
        if (bin > 0 && c + u.h.cnt[bin-1] <= CAP) result = (unsigned)(bin-1); // safety bin
        break;
      }
    }
    thr_sh = result; n_sh = 0u;
  }
  __syncthreads();                      // hist reads done; skeys union reuse below
  const unsigned thr = thr_sh;

  const float4* row4 = (const float4*)(scores + (size_t)r * VOCAB);
  const float4* grn4 = (const float4*)green;
  for (int i = tid; i < V4; i += 1024){
    float4 s = row4[i], g = grn4[i];
    #pragma unroll
    for (int c = 0; c < 4; ++c){
      float l = fmaf(2.f, (&g.x)[c], (&s.x)[c]);
      uint32_t lb = __float_as_uint(l);
      if ((fkey(lb) >> 20) >= thr){
        unsigned pos = atomicAdd(&n_sh, 1u);
        if (pos < CAP) u.skeys[pos] = ((unsigned long long)lb << 32) | (unsigned)(4*i + c);
      }
    }
  }
  __syncthreads();
  unsigned n = n_sh; if (n > CAP) n = CAP;

  for (unsigned j = tid; j < n; j += 1024){
    unsigned long long k = u.skeys[j];
    float l = __uint_as_float((uint32_t)(k >> 32));
    float p = expf(l - m) / D;
    u.skeys[j] = ((unsigned long long)(~__float_as_uint(p)) << 32) | (k & 0xFFFFFFFFull);
  }
  unsigned N2 = 2; while (N2 < n) N2 <<= 1;
  for (unsigned i = n + tid; i < N2; i += 1024) u.skeys[i] = 0xFFFFFFFFFFFFFFFFull;
  __syncthreads();

  for (unsigned k = 2; k <= N2; k <<= 1){
    for (unsigned j = k >> 1; j > 0; j >>= 1){
      for (unsigned i = tid; i < N2; i += 1024){
        unsigned ixj = i ^ j;
        if (ixj > i){
          unsigned long long a = u.skeys[i], c2 = u.skeys[ixj];
          bool up = ((i & k) == 0u);
          if ((a > c2) == up){ u.skeys[i] = c2; u.skeys[ixj] = a; }
        }
      }
      __syncthreads();
    }
  }

  unsigned C = (n + 1023) >> 10;
  {
    unsigned lo = tid * C; if (lo > n) lo = n;
    unsigned hi = lo + C;  if (hi > n) hi = n;
    float s = 0.f;
    for (unsigned j = lo; j < hi; ++j) s += pdecode(u.skeys[j]);
    red[tid] = s;
  }
  __syncthreads();
  if (tid == 0){
    float run = 0.f; int cut = (int)n - 1; int t = 0;
    for (; t < 1024; ++t){ float cs = red[t]; if (run + cs >= 0.9f) break; run += cs; }
    if (t < 1024){
      float c2 = run;
      for (unsigned j = (unsigned)t * C; j < n; ++j){
        c2 += pdecode(u.skeys[j]);
        if (c2 >= 0.9f){ cut = (int)j; break; }
      }
    }
    cut_sh = cut;
  }
  __syncthreads();
  const int cut = cut_sh;

  float best = -INFINITY; unsigned bj = 0x7FFFFFFFu;
  for (int j = tid; j <= cut; j += 1024){
    float p = pdecode(u.skeys[j]);
    float sc = logf(p) + gumbel_at((uint32_t)r * (uint32_t)VOCAB + (uint32_t)j);
    if (sc > best || (sc == best && (unsigned)j < bj)){ best = sc; bj = (unsigned)j; }
  }
  for (int off = 32; off > 0; off >>= 1){
    float osc = __shfl_down(best, off, 64);
    unsigned oj = __shfl_down(bj, off, 64);
    if (osc > best || (osc == best && oj < bj)){ best = osc; bj = oj; }
  }
  if ((tid & 63) == 0){
    uint32_t ub = __float_as_uint(best);
    uint32_t ou = (ub >> 31) ? ~ub : (ub | 0x80000000u);
    wavewin[tid >> 6] = ((unsigned long long)ou << 32) |
                        (unsigned long long)(0xFFFFFFFFu - bj);   // tie -> min j
  }
  __syncthreads();
  if (tid == 0){
    unsigned long long bb = 0ull;
    for (int w = 0; w < 16; ++w){ unsigned long long x = wavewin[w]; if (x > bb) bb = x; }
    unsigned jwin = 0xFFFFFFFFu - (unsigned)(bb & 0xFFFFFFFFull);
    ntok[r] = (unsigned)(u.skeys[jwin] & 0xFFFFFFFFull);
  }
}

// K4: fill the arena-overlapping tail of out (rows FILL_ROWS..255) with 1e-5.
__global__ __launch_bounds__(256) void k_fill_tail(float4* __restrict__ out4){
  const float4 fv = make_float4(1e-5f, 1e-5f, 1e-5f, 1e-5f);
  const int base = FILL_ROWS * V4;
  for (int i = blockIdx.x * 256 + threadIdx.x; i < TAIL_F4; i += (int)gridDim.x * 256)
    out4[base + i] = fv;
}

// K5: scatter winners (after all fills).
__global__ void k_set(float* __restrict__ out, const unsigned* __restrict__ ntok){
  int b = blockIdx.x * blockDim.x + threadIdx.x;
  if (b < BATCH) out[(size_t)b * VOCAB + (size_t)ntok[b]] = 1e5f;
}

extern "C" void kernel_launch(void* const* d_in, const int* in_sizes, int n_in,
                              void* d_out, int out_size, void* d_ws, size_t ws_size,
                              hipStream_t stream) {
  // d_in[0]=input_ids (unused), d_in[1]=scores [256*128000] f32, d_in[2]=green [128000] f32
  const float* scores = (const float*)d_in[1];
  const float* green  = (const float*)d_in[2];
  float* out = (float*)d_out;
  // arena in the tail of d_out (consumed before K4 refills that region)
  float*    abase = out + ABASE;
  unsigned* hcnt  = (unsigned*)abase;                       // 1,048,576 u32
  float*    hmass = (float*)(abase + NBINS*BATCH);          // 1,048,576 f32
  float*    wmax  = abase + HIST_U32;                       // 2048 f32
  float*    wdp   = abase + HIST_U32 + 2048;                // 2048 f32
  unsigned* hzero = hcnt;                                   // 8 MB zero span (hist only)
  unsigned* ntok  = (unsigned*)d_ws;                        // 1 KB — R5-proven ws usage

  hipLaunchKernelGGL(k_fill_max, dim3(BATCH*CHUNKS), dim3(256),  0, stream, scores, green, out, wmax, hzero);
  hipLaunchKernelGGL(k_dsum_hist,dim3(BATCH*CHUNKS), dim3(256),  0, stream, scores, green, wmax, wdp, hcnt, hmass);
  hipLaunchKernelGGL(k_sample,   dim3(BATCH),        dim3(1024), 0, stream, scores, green, wmax, wdp, hcnt, hmass, ntok);
  hipLaunchKernelGGL(k_fill_tail,dim3(2048),         dim3(256),  0, stream, (float4*)out);
  hipLaunchKernelGGL(k_set,      dim3(1),            dim3(256),  0, stream, out, ntok);
}